// Round 15
// baseline (24.455 us; speedup 1.0000x reference)
//
#include <hip/hip_runtime.h>

#define B_ 1024
#define T_ 256
#define C_ 100
#define L_ 64
#define EPS_ 1e-7f
#define LN2 0.69314718055994530942f

#define CH 8                 // timesteps per chunk (3200 B contiguous)
#define NCH 16               // chunks per direction (each wave covers 128 t)
#define SLOTF 832            // floats per slot: [0,800) rows, [800,832) garbage
#define BROW (T_ * C_ * 4)   // bytes per batch element = 102400

#define LOG2F(x) __builtin_amdgcn_logf(x)    // v_log_f32: log2(x)

// inline-asm loads: volatile asm pins issue order vs the counted vmcnt walls
// (compiler sank plain C loads in R8; it cannot reorder volatile asm).
#define GLD4(dst_, addr_, imm_) \
    asm volatile("global_load_dwordx4 %0, %1, off offset:" #imm_ \
                 : "=v"(dst_) : "v"(addr_) : "memory")
#define GLD1(dst_, addr_) \
    asm volatile("global_load_dword %0, %1, off" \
                 : "=v"(dst_) : "v"(addr_) : "memory")
#define WV(n_) asm volatile("s_waitcnt vmcnt(" #n_ ")" ::: "memory")

// whole-wave shifts via DPP; out-of-range lanes get 0 (old=0, bound_ctrl=false)
__device__ __forceinline__ float dpp_shr1(float x) {   // lane i <- lane i-1
    return __int_as_float(__builtin_amdgcn_update_dpp(
        0, __float_as_int(x), 0x138, 0xf, 0xf, false));
}
__device__ __forceinline__ float dpp_shl1(float x) {   // lane i <- lane i+1
    return __int_as_float(__builtin_amdgcn_update_dpp(
        0, __float_as_int(x), 0x130, 0xf, 0xf, false));
}

// Rescale plan: wave-max -> 2^K lifting max to ~1; applied one chunk
// boundary later (stale -> butterfly latency hidden).
#define PLAN(x0_, x1_, x2_) do {                                          \
    float m_ = fmaxf(fmaxf(x0_, x1_), x2_);                               \
    _Pragma("unroll")                                                     \
    for (int d_ = 1; d_ < 64; d_ <<= 1) m_ = fmaxf(m_, __shfl_xor(m_, d_)); \
    const int e_ = (__float_as_int(m_) >> 23) & 255;                      \
    rs_K = 127 - e_;                                                      \
    rs_scale = __int_as_float((254 - e_) << 23);  /* 2^(127-e) */         \
} while (0)

#define APPLY(x0_, x1_, x2_) do { x0_ *= rs_scale; x1_ *= rs_scale;       \
    x2_ *= rs_scale; Sacc += rs_K; } while (0)

// forward step: lane i owns alpha{2i, 2i+1}; lane 63 also alpha{128}
#define FSTEP(pb_, pl_) do {                                              \
    const float up1 = dpp_shr1(a1);                                       \
    const float s   = allow ? up1 : 0.0f;                                 \
    const float n0  = (a0 + up1) * (pb_);                                 \
    const float n1  = ((a1 + a0) + s) * (pl_);                            \
    const float n2  = (a2 + a1) * (pb_);                                  \
    a0 = n0; a1 = n1; a2 = n2;                                            \
} while (0)

// backward step: lane i owns beta{2i, 2i+1}; lane 63 also beta{128}
#define BSTEP(pb_, pl_) do {                                              \
    const float db0 = dpp_shl1(a0);                                       \
    const float db1 = dpp_shl1(a1);                                       \
    const float sc0 = is63 ? a2 : db0;                                    \
    const float sk  = allowN ? db1 : 0.0f;                                \
    const float n0  = (a0 + a1) * (pb_);                                  \
    const float n1  = ((a1 + sc0) + sk) * (pl_);                          \
    const float n2  = a2 * (pb_);                                         \
    a0 = n0; a1 = n1; a2 = n2;                                            \
} while (0)

// issue chunk (3200B + 128B tail garbage) into stage st_ registers
#define LISSUE(st_, off0_) do {                                           \
    const char* ap_ = pA + (off0_);                                       \
    GLD4(sa##st_, ap_, 0);                                                \
    GLD4(sb##st_, ap_, 1024);                                             \
    GLD4(sc##st_, ap_, 2048);                                             \
    unsigned to_ = (unsigned)(off0_) + 3072u + tl4;                       \
    to_ = to_ < (BROW - 4u) ? to_ : (BROW - 4u);                          \
    GLD1(sd##st_, bb + to_);                                              \
} while (0)

// stage -> LDS slot (lane-linear, mirrors the old global_load_lds layout)
#define DSWRITE(st_, slot_) do {                                          \
    float4* s4_ = (float4*)(slot_);                                       \
    s4_[lane]       = sa##st_;                                            \
    s4_[64 + lane]  = sb##st_;                                            \
    s4_[128 + lane] = sc##st_;                                            \
    (slot_)[768 + lane] = sd##st_;                                        \
} while (0)

#define FBODY(sl_) do {                                                   \
    APPLY(a0, a1, a2); PLAN(a0, a1, a2);                                  \
    _Pragma("unroll")                                                     \
    for (int j = 0; j < CH; ++j)                                          \
        FSTEP((sl_)[j * 100 + 99] + EPS_, (sl_)[j * 100 + label] + EPS_); \
} while (0)

#define BBODY(sl_) do {                                                   \
    APPLY(a0, a1, a2); PLAN(a0, a1, a2);                                  \
    _Pragma("unroll")                                                     \
    for (int j = 0; j < CH; ++j)                                          \
        BSTEP((sl_)[(7 - j) * 100 + 99] + EPS_, (sl_)[(7 - j) * 100 + label] + EPS_); \
} while (0)

// Block = 2 waves per batch element: wave 0 = forward alpha (t=0..127),
// wave 1 = backward beta (t=255..128); combine P = sum_s alpha*gamma via LDS.
__global__ __launch_bounds__(128) void ctc_kernel(
    const int* __restrict__ y_true,
    const float* __restrict__ y_pred,
    float* __restrict__ out)
{
    __shared__ float ring[2][2][SLOTF];   // 13.3 KB: 2 slots per direction
    __shared__ float sG0[64], sG1[64];
    __shared__ float sG2;
    __shared__ int   sSaccB;

    const int tid  = threadIdx.x;
    const int lane = tid & 63;
    const int wv   = tid >> 6;              // 0 = alpha, 1 = beta
    const int b    = blockIdx.x;

    const float* __restrict__ base = y_pred + (size_t)b * T_ * C_;
    const char*  __restrict__ bb   = (const char*)base;
    const char*  __restrict__ pA   = bb + ((unsigned)lane << 4);
    const unsigned tl4 = (unsigned)lane << 2;

    const int  label   = y_true[b * L_ + lane];
    const int  labprev = __shfl_up(label, 1);
    const bool allow   = (lane == 0) || (label != labprev);
    const bool is63    = (lane == 63);
    const bool allowN  = (bool)__shfl_down((int)allow, 1);  // lane63: unused

    float4 sa0, sb0, sc0, sa1, sb1, sc1;
    float  sd0, sd1;

    float a0 = 0.0f, a1 = 0.0f, a2 = 0.0f;
    float rs_scale = 1.0f;
    int   rs_K = 0, Sacc = 0;

    if (wv == 0) {
        // ------------- forward wave: chunk c = t in [8c, 8c+8) -------------
        float* __restrict__ s0 = ring[0][0];
        float* __restrict__ s1 = ring[0][1];

        LISSUE(0, 0u);          // c0 -> stage0
        LISSUE(1, 3200u);       // c1 -> stage1
        WV(4);                  // c0 landed
        DSWRITE(0, s0);
        LISSUE(0, 6400u);       // c2 -> stage0   (outstanding: c1, c2)

        #pragma unroll
        for (int c = 0; c < NCH; ++c) {
            if (c <= 13) { WV(4); } else if (c == 14) { WV(0); }
            if (c <= 14) {                      // write chunk c+1 -> slot (c+1)&1
                if (((c + 1) & 1) == 0) { DSWRITE(0, s0); } else { DSWRITE(1, s1); }
            }
            if (c <= 12) {                      // issue chunk c+3 -> stage (c+3)&1
                if (((c + 3) & 1) == 0) { LISSUE(0, (unsigned)(c + 3) * 3200u); }
                else                    { LISSUE(1, (unsigned)(c + 3) * 3200u); }
            }
            const float* __restrict__ sl = (c & 1) ? s1 : s0;
            if (c == 0) {
                a0 = (lane == 0) ? (sl[99] + EPS_) : 0.0f;
                a1 = (lane == 0) ? (sl[label] + EPS_) : 0.0f;
                a2 = 0.0f;
                PLAN(a0, a1, a2);
                #pragma unroll
                for (int j = 1; j < CH; ++j)
                    FSTEP(sl[j * 100 + 99] + EPS_, sl[j * 100 + label] + EPS_);
            } else {
                FBODY(sl);
            }
        }

        // epilogue rescale: lift stored alpha max into [1,2) (no product underflow)
        APPLY(a0, a1, a2);
        PLAN(a0, a1, a2);
        APPLY(a0, a1, a2);
    } else {
        // ---------- backward wave: chunk c = t in [248-8c, 256-8c) ----------
        float* __restrict__ s0 = ring[1][0];
        float* __restrict__ s1 = ring[1][1];

        LISSUE(0, 99200u);      // c0 -> stage0
        LISSUE(1, 96000u);      // c1 -> stage1
        WV(4);
        DSWRITE(0, s0);
        LISSUE(0, 92800u);      // c2 -> stage0

        #pragma unroll
        for (int c = 0; c < NCH; ++c) {
            if (c <= 13) { WV(4); } else if (c == 14) { WV(0); }
            if (c <= 14) {
                if (((c + 1) & 1) == 0) { DSWRITE(0, s0); } else { DSWRITE(1, s1); }
            }
            if (c <= 12) {
                const unsigned o_ = 99200u - (unsigned)(c + 3) * 3200u;
                if (((c + 3) & 1) == 0) { LISSUE(0, o_); } else { LISSUE(1, o_); }
            }
            const float* __restrict__ sl = (c & 1) ? s1 : s0;
            if (c == 0) {
                // t = 255 (slot row 7): paths end in state 127 or 128
                a2 = sl[799] + EPS_;                          // beta[128]
                a1 = is63 ? (sl[700 + label] + EPS_) : 0.0f;  // beta[127]
                a0 = 0.0f;
                PLAN(a0, a1, a2);
                #pragma unroll
                for (int j = 1; j < CH; ++j)
                    BSTEP(sl[(7 - j) * 100 + 99] + EPS_, sl[(7 - j) * 100 + label] + EPS_);
            } else {
                BBODY(sl);
            }
        }

        // epilogue rescale: lift stored beta max into [1,2)
        APPLY(a0, a1, a2);
        PLAN(a0, a1, a2);
        APPLY(a0, a1, a2);

        // gamma at the cut: gamma[s] = sum over succ(s) of beta[t=128][s']
        const float db0 = dpp_shl1(a0);
        const float db1 = dpp_shl1(a1);
        sG0[lane] = a0 + a1;
        sG1[lane] = a1 + (is63 ? a2 : db0) + (allowN ? db1 : 0.0f);
        if (is63) { sG2 = a2; sSaccB = Sacc; }
    }

    __syncthreads();

    if (wv == 0) {
        // P = sum_s alpha[127][s] * gamma[s]
        float prod = a0 * sG0[lane] + a1 * sG1[lane];
        if (is63) prod += a2 * sG2;
        #pragma unroll
        for (int d = 1; d < 64; d <<= 1) prod += __shfl_xor(prod, d);
        if (lane == 0)
            out[b] = -LN2 * (LOG2F(prod) - (float)(Sacc + sSaccB));
    }
}

extern "C" void kernel_launch(void* const* d_in, const int* in_sizes, int n_in,
                              void* d_out, int out_size, void* d_ws, size_t ws_size,
                              hipStream_t stream) {
    const int*   y_true = (const int*)d_in[0];
    const float* y_pred = (const float*)d_in[1];
    float*       out    = (float*)d_out;

    ctc_kernel<<<dim3(B_), dim3(128), 0, stream>>>(y_true, y_pred, out);
}

// Round 16
// 24.323 us; speedup vs baseline: 1.0054x; 1.0054x over previous
//
#include <hip/hip_runtime.h>

#define B_ 1024
#define T_ 256
#define C_ 100
#define L_ 64
#define EPS_ 1e-7f
#define LN2 0.69314718055994530942f

#define CH 8                 // timesteps per chunk (3200 B contiguous)
#define NCH 16               // chunks per direction (each DP wave covers 128 t)
#define SLOTS 5              // ring slots per direction
#define SLOTF 832            // floats per slot: [0,800) rows, [800,832) garbage
#define BROW (T_ * C_ * 4)   // bytes per batch element = 102400

#define LOG2F(x) __builtin_amdgcn_logf(x)    // v_log_f32: log2(x)

typedef const __attribute__((address_space(1))) void GV;
typedef __attribute__((address_space(3))) void LV;

__device__ __forceinline__ void gload_lds16(const void* g, void* l) {
    __builtin_amdgcn_global_load_lds((GV*)g, (LV*)l, 16, 0, 0);
}
__device__ __forceinline__ void gload_lds4(const void* g, void* l) {
    __builtin_amdgcn_global_load_lds((GV*)g, (LV*)l, 4, 0, 0);
}

#define WV(n_) asm volatile("s_waitcnt vmcnt(" #n_ ")" ::: "memory")

// whole-wave shifts via DPP; out-of-range lanes get 0 (old=0, bound_ctrl=false)
__device__ __forceinline__ float dpp_shr1(float x) {   // lane i <- lane i-1
    return __int_as_float(__builtin_amdgcn_update_dpp(
        0, __float_as_int(x), 0x138, 0xf, 0xf, false));
}
__device__ __forceinline__ float dpp_shl1(float x) {   // lane i <- lane i+1
    return __int_as_float(__builtin_amdgcn_update_dpp(
        0, __float_as_int(x), 0x130, 0xf, 0xf, false));
}

// Rescale plan: wave-max -> 2^K lifting max to ~1; applied one chunk
// boundary later (stale -> butterfly latency hidden).
#define PLAN(x0_, x1_, x2_) do {                                          \
    float m_ = fmaxf(fmaxf(x0_, x1_), x2_);                               \
    _Pragma("unroll")                                                     \
    for (int d_ = 1; d_ < 64; d_ <<= 1) m_ = fmaxf(m_, __shfl_xor(m_, d_)); \
    const int e_ = (__float_as_int(m_) >> 23) & 255;                      \
    rs_K = 127 - e_;                                                      \
    rs_scale = __int_as_float((254 - e_) << 23);  /* 2^(127-e) */         \
} while (0)

#define APPLY(x0_, x1_, x2_) do { x0_ *= rs_scale; x1_ *= rs_scale;       \
    x2_ *= rs_scale; Sacc += rs_K; } while (0)

// forward step: lane i owns alpha{2i, 2i+1}; lane 63 also alpha{128}
#define FSTEP(pb_, pl_) do {                                              \
    const float up1 = dpp_shr1(a1);                                       \
    const float s   = allow ? up1 : 0.0f;                                 \
    const float n0  = (a0 + up1) * (pb_);                                 \
    const float n1  = ((a1 + a0) + s) * (pl_);                            \
    const float n2  = (a2 + a1) * (pb_);                                  \
    a0 = n0; a1 = n1; a2 = n2;                                            \
} while (0)

// backward step: lane i owns beta{2i, 2i+1}; lane 63 also beta{128}
#define BSTEP(pb_, pl_) do {                                              \
    const float db0 = dpp_shl1(a0);                                       \
    const float db1 = dpp_shl1(a1);                                       \
    const float sc0 = is63 ? a2 : db0;                                    \
    const float sk  = allowN ? db1 : 0.0f;                                \
    const float n0  = (a0 + a1) * (pb_);                                  \
    const float n1  = ((a1 + sc0) + sk) * (pl_);                          \
    const float n2  = a2 * (pb_);                                         \
    a0 = n0; a1 = n1; a2 = n2;                                            \
} while (0)

// stream chunk into ring slot: 3x1024B + 1x256B coalesced wave-loads covering
// 3200B of rows (+128B tail garbage); per-lane clamp keeps the tail in-bounds.
#define SISSUE(dir_, sidx_, off0_) do {                                   \
    float* __restrict__ slot_ = &ring[dir_][sidx_][0];                    \
    _Pragma("unroll")                                                     \
    for (int k_ = 0; k_ < 3; ++k_)                                        \
        gload_lds16(bb + ((unsigned)(off0_) + k_ * 1024u + ((unsigned)lane << 4)), \
                    slot_ + k_ * 256);                                    \
    {                                                                     \
        unsigned o_ = (unsigned)(off0_) + 3072u + ((unsigned)lane << 2);  \
        o_ = o_ < (BROW - 4u) ? o_ : (BROW - 4u);                         \
        gload_lds4(bb + o_, slot_ + 768);                                 \
    }                                                                     \
} while (0)

#define FBODY(sl_) do {                                                   \
    APPLY(a0, a1, a2); PLAN(a0, a1, a2);                                  \
    _Pragma("unroll")                                                     \
    for (int j = 0; j < CH; ++j)                                          \
        FSTEP((sl_)[j * 100 + 99] + EPS_, (sl_)[j * 100 + label] + EPS_); \
} while (0)

#define BBODY(sl_) do {                                                   \
    APPLY(a0, a1, a2); PLAN(a0, a1, a2);                                  \
    _Pragma("unroll")                                                     \
    for (int j = 0; j < CH; ++j)                                          \
        BSTEP((sl_)[(7 - j) * 100 + 99] + EPS_, (sl_)[(7 - j) * 100 + label] + EPS_); \
} while (0)

// Block = 4 waves per batch element:
//   wave0 = forward-alpha DP (t=0..127)      [consumer]
//   wave1 = backward-beta DP (t=255..128)    [consumer]
//   wave2 = forward producer (streams chunks into ring[0])
//   wave3 = backward producer (streams chunks into ring[1])
// Producers pace on their own counted vmcnt; one __syncthreads per chunk
// publishes slot c to the consumers (m201 STAGE pattern).
__global__ __launch_bounds__(256) void ctc_kernel(
    const int* __restrict__ y_true,
    const float* __restrict__ y_pred,
    float* __restrict__ out)
{
    __shared__ float ring[2][SLOTS][SLOTF];   // 33.3 KB -> 4 blocks/CU
    __shared__ float sG0[64], sG1[64];
    __shared__ float sG2;
    __shared__ int   sSaccB;

    const int tid  = threadIdx.x;
    const int lane = tid & 63;
    const int wave = tid >> 6;              // 0..3
    const int b    = blockIdx.x;

    const float* __restrict__ base = y_pred + (size_t)b * T_ * C_;
    const char*  __restrict__ bb   = (const char*)base;
    const int  label   = y_true[b * L_ + lane];
    const int  labprev = __shfl_up(label, 1);
    const bool allow   = (lane == 0) || (label != labprev);
    const bool is63    = (lane == 63);
    const bool allowN  = (bool)__shfl_down((int)allow, 1);  // lane63: unused

    float a0 = 0.0f, a1 = 0.0f, a2 = 0.0f;
    float rs_scale = 1.0f;
    int   rs_K = 0, Sacc = 0;

    // ---- producer prologue: issue chunks 0..3 of my direction ----
    if (wave >= 2) {
        const int d_ = wave - 2;
        #pragma unroll
        for (int c = 0; c < 4; ++c) {
            const unsigned off = d_ ? (99200u - (unsigned)c * 3200u)
                                    : ((unsigned)c * 3200u);
            SISSUE(d_, c, off);
        }
        WV(12);                              // chunk 0 landed
    }

    #pragma unroll
    for (int c = 0; c < NCH; ++c) {
        __syncthreads();                     // slot c published to consumers

        if (wave == 0) {
            // ---------------- forward DP over chunk c ----------------
            const float* __restrict__ sl = ring[0][c % SLOTS];
            if (c == 0) {
                a0 = (lane == 0) ? (sl[99] + EPS_) : 0.0f;
                a1 = (lane == 0) ? (sl[label] + EPS_) : 0.0f;
                a2 = 0.0f;
                PLAN(a0, a1, a2);
                #pragma unroll
                for (int j = 1; j < CH; ++j)
                    FSTEP(sl[j * 100 + 99] + EPS_, sl[j * 100 + label] + EPS_);
            } else {
                FBODY(sl);
            }
        } else if (wave == 1) {
            // ---------------- backward DP over chunk c ----------------
            const float* __restrict__ sl = ring[1][c % SLOTS];
            if (c == 0) {
                // t = 255 (slot row 7): paths end in state 127 or 128
                a2 = sl[799] + EPS_;                          // beta[128]
                a1 = is63 ? (sl[700 + label] + EPS_) : 0.0f;  // beta[127]
                a0 = 0.0f;
                PLAN(a0, a1, a2);
                #pragma unroll
                for (int j = 1; j < CH; ++j)
                    BSTEP(sl[(7 - j) * 100 + 99] + EPS_, sl[(7 - j) * 100 + label] + EPS_);
            } else {
                BBODY(sl);
            }
        } else {
            // ---------------- producer: stay 4 chunks ahead ----------------
            const int d_ = wave - 2;
            if (c + 4 < NCH) {
                const unsigned off = d_ ? (99200u - (unsigned)(c + 4) * 3200u)
                                        : ((unsigned)(c + 4) * 3200u);
                SISSUE(d_, (c + 4) % SLOTS, off);
            }
            // ensure chunk c+1 is in LDS before the next barrier
            if (c <= 11)      { WV(12); }
            else if (c == 12) { WV(8); }
            else if (c == 13) { WV(4); }
            else if (c == 14) { WV(0); }
        }
    }

    // ---- epilogues ----
    if (wave == 0) {
        // lift stored alpha max into [1,2) (no cross-wave product underflow)
        APPLY(a0, a1, a2);
        PLAN(a0, a1, a2);
        APPLY(a0, a1, a2);
    } else if (wave == 1) {
        APPLY(a0, a1, a2);
        PLAN(a0, a1, a2);
        APPLY(a0, a1, a2);
        // gamma at the cut: gamma[s] = sum over succ(s) of beta[t=128][s']
        const float db0 = dpp_shl1(a0);
        const float db1 = dpp_shl1(a1);
        sG0[lane] = a0 + a1;
        sG1[lane] = a1 + (is63 ? a2 : db0) + (allowN ? db1 : 0.0f);
        if (is63) { sG2 = a2; sSaccB = Sacc; }
    }

    __syncthreads();

    if (wave == 0) {
        // P = sum_s alpha[127][s] * gamma[s]
        float prod = a0 * sG0[lane] + a1 * sG1[lane];
        if (is63) prod += a2 * sG2;
        #pragma unroll
        for (int d = 1; d < 64; d <<= 1) prod += __shfl_xor(prod, d);
        if (lane == 0)
            out[b] = -LN2 * (LOG2F(prod) - (float)(Sacc + sSaccB));
    }
}

extern "C" void kernel_launch(void* const* d_in, const int* in_sizes, int n_in,
                              void* d_out, int out_size, void* d_ws, size_t ws_size,
                              hipStream_t stream) {
    const int*   y_true = (const int*)d_in[0];
    const float* y_pred = (const float*)d_in[1];
    float*       out    = (float*)d_out;

    ctc_kernel<<<dim3(B_), dim3(256), 0, stream>>>(y_true, y_pred, out);
}

// Round 17
// 23.539 us; speedup vs baseline: 1.0389x; 1.0333x over previous
//
#include <hip/hip_runtime.h>

#define B_ 1024
#define T_ 256
#define C_ 100
#define L_ 64
#define EPS_ 1e-7f
#define LN2 0.69314718055994530942f

#define CH 8                 // timesteps per chunk (3200 B contiguous)
#define NCH 16               // chunks per direction (each wave covers 128 t)
#define SLOTS 3              // ring slots per direction (depth-2 pipeline)
#define SLOTF 832            // floats per slot: [0,800) rows, [800,832) garbage
#define BROW (T_ * C_ * 4)   // bytes per batch element = 102400

#define LOG2F(x) __builtin_amdgcn_logf(x)    // v_log_f32: log2(x)

typedef const __attribute__((address_space(1))) void GV;
typedef __attribute__((address_space(3))) void LV;

__device__ __forceinline__ void gload_lds16(const void* g, void* l) {
    __builtin_amdgcn_global_load_lds((GV*)g, (LV*)l, 16, 0, 0);
}
__device__ __forceinline__ void gload_lds4(const void* g, void* l) {
    __builtin_amdgcn_global_load_lds((GV*)g, (LV*)l, 4, 0, 0);
}

// whole-wave shifts via DPP; out-of-range lanes get 0 (old=0, bound_ctrl=false)
__device__ __forceinline__ float dpp_shr1(float x) {   // lane i <- lane i-1
    return __int_as_float(__builtin_amdgcn_update_dpp(
        0, __float_as_int(x), 0x138, 0xf, 0xf, false));
}
__device__ __forceinline__ float dpp_shl1(float x) {   // lane i <- lane i+1
    return __int_as_float(__builtin_amdgcn_update_dpp(
        0, __float_as_int(x), 0x130, 0xf, 0xf, false));
}

// Rescale plan: wave-max -> 2^K lifting max to ~1; applied one chunk
// boundary later (stale -> butterfly latency hidden).
#define PLAN(x0_, x1_, x2_) do {                                          \
    float m_ = fmaxf(fmaxf(x0_, x1_), x2_);                               \
    _Pragma("unroll")                                                     \
    for (int d_ = 1; d_ < 64; d_ <<= 1) m_ = fmaxf(m_, __shfl_xor(m_, d_)); \
    const int e_ = (__float_as_int(m_) >> 23) & 255;                      \
    rs_K = 127 - e_;                                                      \
    rs_scale = __int_as_float((254 - e_) << 23);  /* 2^(127-e) */         \
} while (0)

#define APPLY(x0_, x1_, x2_) do { x0_ *= rs_scale; x1_ *= rs_scale;       \
    x2_ *= rs_scale; Sacc += rs_K; } while (0)

// forward step: lane i owns alpha{2i, 2i+1}; lane 63 also alpha{128}
#define FSTEP(pb_, pl_) do {                                              \
    const float up1 = dpp_shr1(a1);                                       \
    const float s   = allow ? up1 : 0.0f;                                 \
    const float n0  = (a0 + up1) * (pb_);                                 \
    const float n1  = ((a1 + a0) + s) * (pl_);                            \
    const float n2  = (a2 + a1) * (pb_);                                  \
    a0 = n0; a1 = n1; a2 = n2;                                            \
} while (0)

// backward step: lane i owns beta{2i, 2i+1}; lane 63 also beta{128}
#define BSTEP(pb_, pl_) do {                                              \
    const float db0 = dpp_shl1(a0);                                       \
    const float db1 = dpp_shl1(a1);                                       \
    const float sc0 = is63 ? a2 : db0;                                    \
    const float sk  = allowN ? db1 : 0.0f;                                \
    const float n0  = (a0 + a1) * (pb_);                                  \
    const float n1  = ((a1 + sc0) + sk) * (pl_);                          \
    const float n2  = a2 * (pb_);                                         \
    a0 = n0; a1 = n1; a2 = n2;                                            \
} while (0)

// wait until chunk c_'s 4 loads landed (counted vmcnt, never 0 mid-loop)
#define WAITC(c_) do {                                                    \
    if ((c_) <= NCH - 3)      asm volatile("s_waitcnt vmcnt(8)" ::: "memory"); \
    else if ((c_) == NCH - 2) asm volatile("s_waitcnt vmcnt(4)" ::: "memory"); \
    else                      asm volatile("s_waitcnt vmcnt(0)" ::: "memory"); \
} while (0)

// stream chunk into ring slot: 3x1024B + 1x256B coalesced wave-loads covering
// 3200B of rows (+128B tail garbage); per-lane clamp keeps the tail in-bounds.
#define SISSUE(dir_, sidx_, off0_) do {                                   \
    float* __restrict__ slot_ = &ring[dir_][sidx_][0];                    \
    _Pragma("unroll")                                                     \
    for (int k_ = 0; k_ < 3; ++k_)                                        \
        gload_lds16(bb + ((unsigned)(off0_) + k_ * 1024u + ((unsigned)lane << 4)), \
                    slot_ + k_ * 256);                                    \
    {                                                                     \
        unsigned o_ = (unsigned)(off0_) + 3072u + ((unsigned)lane << 2);  \
        o_ = o_ < (BROW - 4u) ? o_ : (BROW - 4u);                         \
        gload_lds4(bb + o_, slot_ + 768);                                 \
    }                                                                     \
} while (0)

#define FBODY(sl_) do {                                                   \
    APPLY(a0, a1, a2); PLAN(a0, a1, a2);                                  \
    _Pragma("unroll")                                                     \
    for (int j = 0; j < CH; ++j)                                          \
        FSTEP((sl_)[j * 100 + 99] + EPS_, (sl_)[j * 100 + label] + EPS_); \
} while (0)

#define BBODY(sl_) do {                                                   \
    APPLY(a0, a1, a2); PLAN(a0, a1, a2);                                  \
    _Pragma("unroll")                                                     \
    for (int j = 0; j < CH; ++j)                                          \
        BSTEP((sl_)[(7 - j) * 100 + 99] + EPS_, (sl_)[(7 - j) * 100 + label] + EPS_); \
} while (0)

// Block = 2 waves per batch element, both self-issuing (barrier-free loop):
// wave 0 = forward alpha (t=0..127), wave 1 = backward beta (t=255..128).
// LDS = exactly 19,968 B -> 8 blocks/CU -> 16 issuing waves/CU (2x R12).
// Combine arrays are overlaid into ring[1][0] after its final consume.
__global__ __launch_bounds__(128) void ctc_kernel(
    const int* __restrict__ y_true,
    const float* __restrict__ y_pred,
    float* __restrict__ out)
{
    __shared__ float ring[2][SLOTS][SLOTF];   // 19,968 B exactly

    // overlay: bwd wave writes these into ring[1][0] AFTER consuming chunk 15
    // (slot 15%3 == 0); fwd wave reads them after the single __syncthreads.
    float* __restrict__ sG0 = &ring[1][0][0];     // [64]
    float* __restrict__ sG1 = &ring[1][0][64];    // [64]
    float* __restrict__ sG2p = &ring[1][0][128];
    int*   __restrict__ sSp  = (int*)&ring[1][0][129];

    const int tid  = threadIdx.x;
    const int lane = tid & 63;
    const int wv   = tid >> 6;              // 0 = alpha, 1 = beta
    const int b    = blockIdx.x;

    const float* __restrict__ base = y_pred + (size_t)b * T_ * C_;
    const char*  __restrict__ bb   = (const char*)base;
    const int  label   = y_true[b * L_ + lane];
    const int  labprev = __shfl_up(label, 1);
    const bool allow   = (lane == 0) || (label != labprev);
    const bool is63    = (lane == 63);
    const bool allowN  = (bool)__shfl_down((int)allow, 1);  // lane63: unused

    float a0 = 0.0f, a1 = 0.0f, a2 = 0.0f;
    float rs_scale = 1.0f;
    int   rs_K = 0, Sacc = 0;

    if (wv == 0) {
        // ------------- forward wave: chunk c = t in [8c, 8c+8) -------------
        SISSUE(0, 0, 0u); SISSUE(0, 1, 3200u);

        #pragma unroll
        for (int c = 0; c < NCH; ++c) {
            if (c + 2 < NCH) SISSUE(0, (c + 2) % SLOTS, (unsigned)(c + 2) * 3200u);
            WAITC(c);
            const float* __restrict__ sl = ring[0][c % SLOTS];
            if (c == 0) {
                a0 = (lane == 0) ? (sl[99] + EPS_) : 0.0f;
                a1 = (lane == 0) ? (sl[label] + EPS_) : 0.0f;
                a2 = 0.0f;
                PLAN(a0, a1, a2);
                #pragma unroll
                for (int j = 1; j < CH; ++j)
                    FSTEP(sl[j * 100 + 99] + EPS_, sl[j * 100 + label] + EPS_);
            } else {
                FBODY(sl);
            }
        }

        // epilogue rescale: lift stored alpha max into [1,2) (no product underflow)
        APPLY(a0, a1, a2);
        PLAN(a0, a1, a2);
        APPLY(a0, a1, a2);
    } else {
        // ---------- backward wave: chunk c = t in [248-8c, 256-8c) ----------
        SISSUE(1, 0, 99200u); SISSUE(1, 1, 96000u);

        #pragma unroll
        for (int c = 0; c < NCH; ++c) {
            if (c + 2 < NCH) SISSUE(1, (c + 2) % SLOTS, 99200u - (unsigned)(c + 2) * 3200u);
            WAITC(c);
            const float* __restrict__ sl = ring[1][c % SLOTS];
            if (c == 0) {
                // t = 255 (slot row 7): paths end in state 127 or 128
                a2 = sl[799] + EPS_;                          // beta[128]
                a1 = is63 ? (sl[700 + label] + EPS_) : 0.0f;  // beta[127]
                a0 = 0.0f;
                PLAN(a0, a1, a2);
                #pragma unroll
                for (int j = 1; j < CH; ++j)
                    BSTEP(sl[(7 - j) * 100 + 99] + EPS_, sl[(7 - j) * 100 + label] + EPS_);
            } else {
                BBODY(sl);
            }
        }

        // epilogue rescale: lift stored beta max into [1,2)
        APPLY(a0, a1, a2);
        PLAN(a0, a1, a2);
        APPLY(a0, a1, a2);

        // gamma at the cut: gamma[s] = sum over succ(s) of beta[t=128][s']
        // (slot 0 was consumed above at c=15; safe to overwrite with sG)
        const float db0 = dpp_shl1(a0);
        const float db1 = dpp_shl1(a1);
        sG0[lane] = a0 + a1;
        sG1[lane] = a1 + (is63 ? a2 : db0) + (allowN ? db1 : 0.0f);
        if (is63) { *sG2p = a2; *sSp = Sacc; }
    }

    __syncthreads();

    if (wv == 0) {
        // P = sum_s alpha[127][s] * gamma[s]
        float prod = a0 * sG0[lane] + a1 * sG1[lane];
        if (is63) prod += a2 * (*sG2p);
        #pragma unroll
        for (int d = 1; d < 64; d <<= 1) prod += __shfl_xor(prod, d);
        if (lane == 0)
            out[b] = -LN2 * (LOG2F(prod) - (float)(Sacc + *sSp));
    }
}

extern "C" void kernel_launch(void* const* d_in, const int* in_sizes, int n_in,
                              void* d_out, int out_size, void* d_ws, size_t ws_size,
                              hipStream_t stream) {
    const int*   y_true = (const int*)d_in[0];
    const float* y_pred = (const float*)d_in[1];
    float*       out    = (float*)d_out;

    ctc_kernel<<<dim3(B_), dim3(128), 0, stream>>>(y_true, y_pred, out);
}